// Round 11
// baseline (85.152 us; speedup 1.0000x reference)
//
#include <hip/hip_runtime.h>
#include <hip/hip_bf16.h>

#define BB 2
#define TT 15
#define NN 2048
#define TO 8
#define MM 64
#define KH 32
#define DIMD 512
#define R2 0.49f

typedef float v2f __attribute__((ext_vector_type(2)));
typedef unsigned long long ull;

// DPP cross-lane helper (VALU)
template<int CTRL>
__device__ __forceinline__ unsigned dppu(unsigned x) {
    return (unsigned)__builtin_amdgcn_update_dpp((int)x, (int)x, CTRL, 0xF, 0xF, false);
}

// standard GCN wave64 inclusive add-scan on VALU DPP (replaces 6 dependent ds_bpermute)
__device__ __forceinline__ int wave_incl_scan(int x) {
    int s = x;
    s += __builtin_amdgcn_update_dpp(0, s, 0x111, 0xF, 0xF, true);   // row_shr:1
    s += __builtin_amdgcn_update_dpp(0, s, 0x112, 0xF, 0xF, true);   // row_shr:2
    s += __builtin_amdgcn_update_dpp(0, s, 0x114, 0xF, 0xF, true);   // row_shr:4
    s += __builtin_amdgcn_update_dpp(0, s, 0x118, 0xF, 0xF, true);   // row_shr:8
    s += __builtin_amdgcn_update_dpp(0, s, 0x142, 0xA, 0xF, false);  // row_bcast15 -> rows 1,3
    s += __builtin_amdgcn_update_dpp(0, s, 0x143, 0xC, 0xF, false);  // row_bcast31 -> rows 2,3
    return s;
}

// ---------------- FPS v11: pk dist + coord-carrying tree + ONE LDS round-trip ----------------
// 16 blocks x 256 threads (4 waves); thread owns 8 consecutive points as 4 float2 pairs.
__global__ __launch_bounds__(256) void fps_kernel(const float* __restrict__ input,
                                                  float* __restrict__ anchor_xyz) {
#pragma clang fp contract(off)
    __shared__ float4 sA[2][4];     // (keyhi, keylo, x, y) per wave, ping-pong
    __shared__ float  sB[2][4];     // z per wave
    __shared__ float  wout[MM * 3]; // staged winner coords
    int blk = blockIdx.x;           // 0..15 = b*8+f
    int b = blk >> 3, f = blk & 7;
    const float* src = input + ((size_t)(b * TT + 2 * f)) * NN * 3;
    int tid = threadIdx.x, w = tid >> 6;

    const float4* s4 = (const float4*)(src + tid * 24);
    float4 v0 = s4[0], v1 = s4[1], v2 = s4[2], v3 = s4[3], v4 = s4[4], v5 = s4[5];

    // pair p covers points j=2p, 2p+1 (global index = tid*8+j)
    v2f PX[4], PY[4], PZ[4], MD[4];
    PX[0] = (v2f){v0.x, v0.w}; PY[0] = (v2f){v0.y, v1.x}; PZ[0] = (v2f){v0.z, v1.y};
    PX[1] = (v2f){v1.z, v2.y}; PY[1] = (v2f){v1.w, v2.z}; PZ[1] = (v2f){v2.x, v2.w};
    PX[2] = (v2f){v3.x, v3.w}; PY[2] = (v2f){v3.y, v4.x}; PZ[2] = (v2f){v3.z, v4.y};
    PX[3] = (v2f){v4.z, v5.y}; PY[3] = (v2f){v4.w, v5.z}; PZ[3] = (v2f){v5.x, v5.w};
#pragma unroll
    for (int p = 0; p < 4; ++p) MD[p] = (v2f){1e10f, 1e10f};
    unsigned base = (unsigned)(NN - tid * 8);   // lo_j = base - j

    // seed: point 0 (uniform scalar loads -> broadcast)
    float lx = src[0], ly = src[1], lz = src[2];
    if (tid == 0) { wout[0] = lx; wout[1] = ly; wout[2] = lz; }

    for (int it = 1; it < MM; ++it) {
        int pp = it & 1;
        // packed distance update: per-half IEEE-identical; contract(off) keeps
        // ((dx*dx + dy*dy) + dz*dz) mul/add order bitwise == numpy.
        v2f L0 = (v2f){lx, lx}, L1 = (v2f){ly, ly}, L2 = (v2f){lz, lz};
#pragma unroll
        for (int p = 0; p < 4; ++p) {
            v2f dx = PX[p] - L0, dy = PY[p] - L1, dz = PZ[p] - L2;
            v2f u1 = dx * dx, u2 = dy * dy, u3 = dz * dz;
            v2f d = (u1 + u2) + u3;
            MD[p] = __builtin_elementwise_min(MD[p], d);
        }
        // candidates: key = (bits(m)<<32) | (2048-i) (unique); carry coords thru tree
        ull k[8]; float cx[8], cy[8], cz[8];
#pragma unroll
        for (int p = 0; p < 4; ++p) {
            k[2 * p]     = (((ull)__float_as_uint(MD[p].x)) << 32) | (ull)(base - 2 * p);
            k[2 * p + 1] = (((ull)__float_as_uint(MD[p].y)) << 32) | (ull)(base - 2 * p - 1);
            cx[2 * p] = PX[p].x; cy[2 * p] = PY[p].x; cz[2 * p] = PZ[p].x;
            cx[2 * p + 1] = PX[p].y; cy[2 * p + 1] = PY[p].y; cz[2 * p + 1] = PZ[p].y;
        }
#pragma unroll
        for (int st = 1; st < 8; st <<= 1)
#pragma unroll
            for (int j = 0; j < 8; j += 2 * st)
                if (k[j + st] > k[j]) {
                    k[j] = k[j + st]; cx[j] = cx[j + st]; cy[j] = cy[j + st]; cz[j] = cz[j + st];
                }
        ull myk = k[0];
        unsigned khi = (unsigned)(myk >> 32), klo = (unsigned)myk;

        // key-only wave argmax via DPP; full max lands in lane 63
#define DPP_STEP(CTRL) { \
            unsigned ohi = dppu<CTRL>(khi), olo = dppu<CTRL>(klo); \
            ull ok = (((ull)ohi) << 32) | olo, ck = (((ull)khi) << 32) | klo; \
            if (ok > ck) { khi = ohi; klo = olo; } }
        DPP_STEP(0xB1)   // quad_perm xor1
        DPP_STEP(0x4E)   // quad_perm xor2
        DPP_STEP(0x141)  // row_half_mirror
        DPP_STEP(0x140)  // row_mirror
        DPP_STEP(0x142)  // row_bcast15
        DPP_STEP(0x143)  // row_bcast31
#undef DPP_STEP
        ull wmax = (((ull)(unsigned)__builtin_amdgcn_readlane((int)khi, 63)) << 32)
                 |  (ull)(unsigned)__builtin_amdgcn_readlane((int)klo, 63);
        // exactly one lane per wave owns the max key -> it writes key+coords (ONE LDS trip)
        if (myk == wmax) {
            sA[pp][w] = make_float4(__uint_as_float((unsigned)(wmax >> 32)),
                                    __uint_as_float((unsigned)wmax), cx[0], cy[0]);
            sB[pp][w] = cz[0];
        }
        __syncthreads();
        float4 a0 = sA[pp][0], a1 = sA[pp][1], a2 = sA[pp][2], a3 = sA[pp][3];
        float b0 = sB[pp][0], b1 = sB[pp][1], b2 = sB[pp][2], b3 = sB[pp][3];
        ull q0 = (((ull)__float_as_uint(a0.x)) << 32) | __float_as_uint(a0.y);
        ull q1 = (((ull)__float_as_uint(a1.x)) << 32) | __float_as_uint(a1.y);
        ull q2 = (((ull)__float_as_uint(a2.x)) << 32) | __float_as_uint(a2.y);
        ull q3 = (((ull)__float_as_uint(a3.x)) << 32) | __float_as_uint(a3.y);
        if (q1 > q0) { q0 = q1; a0.z = a1.z; a0.w = a1.w; b0 = b1; }
        if (q3 > q2) { q2 = q3; a2.z = a3.z; a2.w = a3.w; b2 = b3; }
        if (q2 > q0) { q0 = q2; a0.z = a2.z; a0.w = a2.w; b0 = b2; }
        lx = a0.z; ly = a0.w; lz = b0;   // block-uniform winner coords
        if (tid == 0) { wout[it * 3 + 0] = lx; wout[it * 3 + 1] = ly; wout[it * 3 + 2] = lz; }
        // single barrier per iter: ping-pong handles WAR across iterations
    }

    // one coalesced global write of all winners at the end
    __syncthreads();
    float* out = anchor_xyz + (size_t)blk * MM * 3;
    if (tid < MM * 3) out[tid] = wout[tid];
}

// ---------------- Encode v2: hoisted loads + DPP scan + float4 hits + pk-FMA ----------------
__global__ __launch_bounds__(256) void encode_kernel(const float* __restrict__ input,
                                                     const float* __restrict__ W_d,
                                                     const float* __restrict__ W_f,
                                                     const float* __restrict__ W_pos,
                                                     const float* __restrict__ b_pos,
                                                     const float* __restrict__ anchor_xyz,
                                                     float* __restrict__ outp) {
    __shared__ float4 hxyz[2][KH];    // hit coords (x,y,z,-), ping-pong
    __shared__ int swtot[2][4];
    int bid = blockIdx.x;                 // b*512 + f*64 + m
    int b = bid >> 9;
    int rem = bid & 511;
    int f = rem >> 6;
    int m = rem & 63;
    int tid = threadIdx.x, lane = tid & 63, w = tid >> 6;

    const float* anc = anchor_xyz + (size_t)(((b << 3) + f) * MM + m) * 3;
    float ax = anc[0], ay = anc[1], az = anc[2];

    int d0 = tid, d1 = tid + 256;
    float4 wd0 = ((const float4*)W_d)[d0];
    float4 wd1 = ((const float4*)W_d)[d1];
    float  wf0 = W_f[d0], wf1 = W_f[d1];
    // pack the thread's two output dims into v2f lanes
    v2f WX = (v2f){wd0.x, wd1.x}, WY = (v2f){wd0.y, wd1.y};
    v2f WZ = (v2f){wd0.z, wd1.z}, WW = (v2f){wd0.w, wd1.w};
    v2f WF = (v2f){wf0, wf1};
    v2f P = (v2f){-INFINITY, -INFINITY}, Q = (v2f){-INFINITY, -INFINITY};

    // hoist all 3 frames' point loads (hides global latency under dt=0 compute)
    float4 V[3][6];
#pragma unroll
    for (int q = 0; q < 3; ++q) {
        int frame = 2 * f + q - 1;
        frame = frame < 0 ? 0 : (frame > 14 ? 14 : frame);
        const float4* s4 = (const float4*)(input + ((size_t)(b * TT + frame)) * NN * 3 + tid * 24);
#pragma unroll
        for (int i = 0; i < 6; ++i) V[q][i] = s4[i];
    }

#pragma unroll
    for (int q = 0; q < 3; ++q) {
        int pp = q & 1;
        float4 v0 = V[q][0], v1 = V[q][1], v2 = V[q][2], v3 = V[q][3], v4 = V[q][4], v5 = V[q][5];
        float px[8], py[8], pz[8];
        px[0] = v0.x; py[0] = v0.y; pz[0] = v0.z;
        px[1] = v0.w; py[1] = v1.x; pz[1] = v1.y;
        px[2] = v1.z; py[2] = v1.w; pz[2] = v2.x;
        px[3] = v2.y; py[3] = v2.z; pz[3] = v2.w;
        px[4] = v3.x; py[4] = v3.y; pz[4] = v3.z;
        px[5] = v3.w; py[5] = v4.x; pz[5] = v4.y;
        px[6] = v4.z; py[6] = v4.w; pz[6] = v5.x;
        px[7] = v5.y; py[7] = v5.z; pz[7] = v5.w;

        unsigned hit = 0; int cnt = 0;
#pragma unroll
        for (int j = 0; j < 8; ++j) {
            float dx = ax - px[j], dy = ay - py[j], dz = az - pz[j];
            // discrete path: exact no-FMA order, matches numpy bitwise
            float d2 = __fadd_rn(__fadd_rn(__fmul_rn(dx, dx), __fmul_rn(dy, dy)),
                                 __fmul_rn(dz, dz));
            if (d2 < R2) { hit |= 1u << j; cnt++; }
        }
        // wave inclusive scan on VALU DPP (was 6 dependent ds_bpermute)
        int s = wave_incl_scan(cnt);
        if (lane == 63) swtot[pp][w] = s;
        __syncthreads();
        int wavebase = 0, total = 0;
#pragma unroll
        for (int ww = 0; ww < 4; ++ww) {
            int t2 = swtot[pp][ww];
            total += t2;
            if (ww < w) wavebase += t2;
        }
        int r = wavebase + s - cnt;   // exclusive global rank of this thread's first hit
#pragma unroll
        for (int j = 0; j < 8; ++j) {
            if (hit & (1u << j)) {
                if (r < KH) hxyz[pp][r] = make_float4(px[j], py[j], pz[j], 0.f);
                r++;
            }
        }
        if (total == 0 && tid == 0) hxyz[pp][0] = make_float4(px[0], py[0], pz[0], 0.f);
        __syncthreads();

        int nh = (total == 0) ? 1 : (total < KH ? total : KH);
        float dtf = (float)(q - 1);
        v2f DTW = (v2f){dtf, dtf} * WW;   // constant per dt
        // pk-FMA feature loop: 1 ds_read_b128 + ~5 pk ops per neighbor; P/Q for ILP
        int k = 0;
        for (; k + 2 <= nh; k += 2) {
            float4 g0 = hxyz[pp][k], g1 = hxyz[pp][k + 1];
            v2f u0 = DTW, u1 = DTW;
            u0 += (v2f){g0.z, g0.z} * WF;            u1 += (v2f){g1.z, g1.z} * WF;
            u0 += (v2f){g0.x - ax, g0.x - ax} * WX;  u1 += (v2f){g1.x - ax, g1.x - ax} * WX;
            u0 += (v2f){g0.y - ay, g0.y - ay} * WY;  u1 += (v2f){g1.y - ay, g1.y - ay} * WY;
            u0 += (v2f){g0.z - az, g0.z - az} * WZ;  u1 += (v2f){g1.z - az, g1.z - az} * WZ;
            P = __builtin_elementwise_max(P, u0);
            Q = __builtin_elementwise_max(Q, u1);
        }
        if (k < nh) {
            float4 g0 = hxyz[pp][k];
            v2f u0 = DTW;
            u0 += (v2f){g0.z, g0.z} * WF;
            u0 += (v2f){g0.x - ax, g0.x - ax} * WX;
            u0 += (v2f){g0.y - ay, g0.y - ay} * WY;
            u0 += (v2f){g0.z - az, g0.z - az} * WZ;
            P = __builtin_elementwise_max(P, u0);
        }
        // no trailing barrier: ping-pong buffers handle WAR across dt
    }
    P = __builtin_elementwise_max(P, Q);

    // epilogue: positional linear + bias + relu, float32 store
    float4 wp0 = ((const float4*)W_pos)[d0];
    float4 wp1 = ((const float4*)W_pos)[d1];
    float tv = (float)(f + 1);
    float pos0 = ax * wp0.x + ay * wp0.y + az * wp0.z + tv * wp0.w + b_pos[d0];
    float pos1 = ax * wp1.x + ay * wp1.y + az * wp1.z + tv * wp1.w + b_pos[d1];
    float o0 = fmaxf(pos0 + P.x, 0.0f);
    float o1 = fmaxf(pos1 + P.y, 0.0f);
    size_t row = ((size_t)b * (TO * MM) + f * MM + m) * DIMD;
    outp[row + d0] = o0;
    outp[row + d1] = o1;
}

extern "C" void kernel_launch(void* const* d_in, const int* in_sizes, int n_in,
                              void* d_out, int out_size, void* d_ws, size_t ws_size,
                              hipStream_t stream) {
    const float* input = (const float*)d_in[0];
    const float* W_d   = (const float*)d_in[1];
    const float* W_f   = (const float*)d_in[2];
    const float* W_pos = (const float*)d_in[3];
    const float* b_pos = (const float*)d_in[4];
    float* anchor = (float*)d_ws;   // 16*64*3 floats = 12 KB

    fps_kernel<<<16, 256, 0, stream>>>(input, anchor);
    encode_kernel<<<1024, 256, 0, stream>>>(input, W_d, W_f, W_pos, b_pos, anchor,
                                            (float*)d_out);
}

// Round 12
// 50.147 us; speedup vs baseline: 1.6981x; 1.6981x over previous
//
#include <hip/hip_runtime.h>
#include <hip/hip_bf16.h>

#define BB 2
#define TT 15
#define NN 2048
#define TO 8
#define MM 64
#define KH 32
#define DIMD 512
#define R2 0.49f

typedef float v2f __attribute__((ext_vector_type(2)));
typedef unsigned long long ull;

// DPP cross-lane helper (VALU)
template<int CTRL>
__device__ __forceinline__ unsigned dppu(unsigned x) {
    return (unsigned)__builtin_amdgcn_update_dpp((int)x, (int)x, CTRL, 0xF, 0xF, false);
}

// standard GCN wave64 inclusive add-scan on VALU DPP (validated bit-exact in r11)
__device__ __forceinline__ int wave_incl_scan(int x) {
    int s = x;
    s += __builtin_amdgcn_update_dpp(0, s, 0x111, 0xF, 0xF, true);   // row_shr:1
    s += __builtin_amdgcn_update_dpp(0, s, 0x112, 0xF, 0xF, true);   // row_shr:2
    s += __builtin_amdgcn_update_dpp(0, s, 0x114, 0xF, 0xF, true);   // row_shr:4
    s += __builtin_amdgcn_update_dpp(0, s, 0x118, 0xF, 0xF, true);   // row_shr:8
    s += __builtin_amdgcn_update_dpp(0, s, 0x142, 0xA, 0xF, false);  // row_bcast15 -> rows 1,3
    s += __builtin_amdgcn_update_dpp(0, s, 0x143, 0xC, 0xF, false);  // row_bcast31 -> rows 2,3
    return s;
}

// ---------------- FPS v10 (verbatim revert — best measured ~30us) ----------------
// pk-math dist + key-only reduce + LDS coord table; 16 blocks x 256 threads.
__global__ __launch_bounds__(256) void fps_kernel(const float* __restrict__ input,
                                                  float* __restrict__ anchor_xyz) {
#pragma clang fp contract(off)
    __shared__ float sxyz[NN * 3];      // 24KB AoS coord table (winner lookup)
    __shared__ ull   sK[2][4];          // per-wave keys, ping-pong
    __shared__ float wout[MM * 3];      // staged winner coords
    int blk = blockIdx.x;               // 0..15 = b*8+f
    int b = blk >> 3, f = blk & 7;
    const float* src = input + ((size_t)(b * TT + 2 * f)) * NN * 3;
    int tid = threadIdx.x, w = tid >> 6;

    // load 8 points (24 floats = 6 float4), stage to LDS, keep in regs as pairs
    const float4* s4 = (const float4*)(src + tid * 24);
    float4 v0 = s4[0], v1 = s4[1], v2 = s4[2], v3 = s4[3], v4 = s4[4], v5 = s4[5];
    float4* l4 = (float4*)(sxyz + tid * 24);
    l4[0] = v0; l4[1] = v1; l4[2] = v2; l4[3] = v3; l4[4] = v4; l4[5] = v5;

    // pair p covers points j=2p, 2p+1 (j local; global index = tid*8+j)
    v2f PX[4], PY[4], PZ[4], MD[4];
    PX[0] = (v2f){v0.x, v0.w}; PY[0] = (v2f){v0.y, v1.x}; PZ[0] = (v2f){v0.z, v1.y};
    PX[1] = (v2f){v1.z, v2.y}; PY[1] = (v2f){v1.w, v2.z}; PZ[1] = (v2f){v2.x, v2.w};
    PX[2] = (v2f){v3.x, v3.w}; PY[2] = (v2f){v3.y, v4.x}; PZ[2] = (v2f){v3.z, v4.y};
    PX[3] = (v2f){v4.z, v5.y}; PY[3] = (v2f){v4.w, v5.z}; PZ[3] = (v2f){v5.x, v5.w};
#pragma unroll
    for (int p = 0; p < 4; ++p) MD[p] = (v2f){1e10f, 1e10f};
    unsigned base = (unsigned)(NN - tid * 8);   // lo_j = base - j

    // seed: point 0 (uniform scalar loads -> broadcast)
    float lx = src[0], ly = src[1], lz = src[2];
    if (tid == 0) { wout[0] = lx; wout[1] = ly; wout[2] = lz; }

    for (int it = 1; it < MM; ++it) {
        int pp = it & 1;
        // packed distance update: v_pk_{add,mul,min}_f32 — IEEE-identical per half,
        // contract(off) keeps ((dx*dx + dy*dy) + dz*dz) mul/add order bitwise.
        v2f L0 = (v2f){lx, lx}, L1 = (v2f){ly, ly}, L2 = (v2f){lz, lz};
#pragma unroll
        for (int p = 0; p < 4; ++p) {
            v2f dx = PX[p] - L0, dy = PY[p] - L1, dz = PZ[p] - L2;
            v2f u1 = dx * dx, u2 = dy * dy, u3 = dz * dz;
            v2f d = (u1 + u2) + u3;
            MD[p] = __builtin_elementwise_min(MD[p], d);
        }
        // keys: (bits(m) << 32) | (2048 - i)  — unique, u64 max == (max m, tie -> min i)
        ull k[8];
#pragma unroll
        for (int p = 0; p < 4; ++p) {
            k[2 * p]     = (((ull)__float_as_uint(MD[p].x)) << 32) | (ull)(base - 2 * p);
            k[2 * p + 1] = (((ull)__float_as_uint(MD[p].y)) << 32) | (ull)(base - 2 * p - 1);
        }
        // in-thread tree (assoc+comm, keys unique -> order-free)
#pragma unroll
        for (int st = 1; st < 8; st <<= 1)
#pragma unroll
            for (int j = 0; j < 8; j += 2 * st)
                if (k[j + st] > k[j]) k[j] = k[j + st];
        unsigned khi = (unsigned)(k[0] >> 32), klo = (unsigned)k[0];

        // key-only wave argmax via DPP; full max lands in lane 63
#define DPP_STEP(CTRL) { \
            unsigned ohi = dppu<CTRL>(khi), olo = dppu<CTRL>(klo); \
            ull ok = (((ull)ohi) << 32) | olo, ck = (((ull)khi) << 32) | klo; \
            if (ok > ck) { khi = ohi; klo = olo; } }
        DPP_STEP(0xB1)   // quad_perm xor1
        DPP_STEP(0x4E)   // quad_perm xor2
        DPP_STEP(0x141)  // row_half_mirror
        DPP_STEP(0x140)  // row_mirror
        DPP_STEP(0x142)  // row_bcast15
        DPP_STEP(0x143)  // row_bcast31
#undef DPP_STEP
        if ((tid & 63) == 63) sK[pp][w] = (((ull)khi) << 32) | klo;
        __syncthreads();
        ull k0 = sK[pp][0], k1 = sK[pp][1], k2 = sK[pp][2], k3 = sK[pp][3];
        if (k1 > k0) k0 = k1;
        if (k3 > k2) k2 = k3;
        if (k2 > k0) k0 = k2;
        unsigned widx = NN - (unsigned)k0;      // block-uniform winner index
        lx = sxyz[3 * widx]; ly = sxyz[3 * widx + 1]; lz = sxyz[3 * widx + 2];  // broadcast reads
        if (tid == 0) { wout[it * 3 + 0] = lx; wout[it * 3 + 1] = ly; wout[it * 3 + 2] = lz; }
        // single barrier per iter: sK ping-pong handles WAR across iterations
    }

    // one coalesced global write of all winners at the end
    __syncthreads();
    float* out = anchor_xyz + (size_t)blk * MM * 3;
    if (tid < MM * 3) out[tid] = wout[tid];
}

// ---------------- Encode v2 (kept from r11 — validated bit-exact) ----------------
__global__ __launch_bounds__(256) void encode_kernel(const float* __restrict__ input,
                                                     const float* __restrict__ W_d,
                                                     const float* __restrict__ W_f,
                                                     const float* __restrict__ W_pos,
                                                     const float* __restrict__ b_pos,
                                                     const float* __restrict__ anchor_xyz,
                                                     float* __restrict__ outp) {
    __shared__ float4 hxyz[2][KH];    // hit coords (x,y,z,-), ping-pong
    __shared__ int swtot[2][4];
    int bid = blockIdx.x;                 // b*512 + f*64 + m
    int b = bid >> 9;
    int rem = bid & 511;
    int f = rem >> 6;
    int m = rem & 63;
    int tid = threadIdx.x, lane = tid & 63, w = tid >> 6;

    const float* anc = anchor_xyz + (size_t)(((b << 3) + f) * MM + m) * 3;
    float ax = anc[0], ay = anc[1], az = anc[2];

    int d0 = tid, d1 = tid + 256;
    float4 wd0 = ((const float4*)W_d)[d0];
    float4 wd1 = ((const float4*)W_d)[d1];
    float  wf0 = W_f[d0], wf1 = W_f[d1];
    // pack the thread's two output dims into v2f lanes
    v2f WX = (v2f){wd0.x, wd1.x}, WY = (v2f){wd0.y, wd1.y};
    v2f WZ = (v2f){wd0.z, wd1.z}, WW = (v2f){wd0.w, wd1.w};
    v2f WF = (v2f){wf0, wf1};
    v2f P = (v2f){-INFINITY, -INFINITY}, Q = (v2f){-INFINITY, -INFINITY};

    // hoist all 3 frames' point loads (hides global latency under dt=0 compute)
    float4 V[3][6];
#pragma unroll
    for (int q = 0; q < 3; ++q) {
        int frame = 2 * f + q - 1;
        frame = frame < 0 ? 0 : (frame > 14 ? 14 : frame);
        const float4* s4 = (const float4*)(input + ((size_t)(b * TT + frame)) * NN * 3 + tid * 24);
#pragma unroll
        for (int i = 0; i < 6; ++i) V[q][i] = s4[i];
    }

#pragma unroll
    for (int q = 0; q < 3; ++q) {
        int pp = q & 1;
        float4 v0 = V[q][0], v1 = V[q][1], v2 = V[q][2], v3 = V[q][3], v4 = V[q][4], v5 = V[q][5];
        float px[8], py[8], pz[8];
        px[0] = v0.x; py[0] = v0.y; pz[0] = v0.z;
        px[1] = v0.w; py[1] = v1.x; pz[1] = v1.y;
        px[2] = v1.z; py[2] = v1.w; pz[2] = v2.x;
        px[3] = v2.y; py[3] = v2.z; pz[3] = v2.w;
        px[4] = v3.x; py[4] = v3.y; pz[4] = v3.z;
        px[5] = v3.w; py[5] = v4.x; pz[5] = v4.y;
        px[6] = v4.z; py[6] = v4.w; pz[6] = v5.x;
        px[7] = v5.y; py[7] = v5.z; pz[7] = v5.w;

        unsigned hit = 0; int cnt = 0;
#pragma unroll
        for (int j = 0; j < 8; ++j) {
            float dx = ax - px[j], dy = ay - py[j], dz = az - pz[j];
            // discrete path: exact no-FMA order, matches numpy bitwise
            float d2 = __fadd_rn(__fadd_rn(__fmul_rn(dx, dx), __fmul_rn(dy, dy)),
                                 __fmul_rn(dz, dz));
            if (d2 < R2) { hit |= 1u << j; cnt++; }
        }
        // wave inclusive scan on VALU DPP (was 6 dependent ds_bpermute)
        int s = wave_incl_scan(cnt);
        if (lane == 63) swtot[pp][w] = s;
        __syncthreads();
        int wavebase = 0, total = 0;
#pragma unroll
        for (int ww = 0; ww < 4; ++ww) {
            int t2 = swtot[pp][ww];
            total += t2;
            if (ww < w) wavebase += t2;
        }
        int r = wavebase + s - cnt;   // exclusive global rank of this thread's first hit
#pragma unroll
        for (int j = 0; j < 8; ++j) {
            if (hit & (1u << j)) {
                if (r < KH) hxyz[pp][r] = make_float4(px[j], py[j], pz[j], 0.f);
                r++;
            }
        }
        if (total == 0 && tid == 0) hxyz[pp][0] = make_float4(px[0], py[0], pz[0], 0.f);
        __syncthreads();

        int nh = (total == 0) ? 1 : (total < KH ? total : KH);
        float dtf = (float)(q - 1);
        v2f DTW = (v2f){dtf, dtf} * WW;   // constant per dt
        // pk-FMA feature loop: 1 ds_read_b128 + ~5 pk ops per neighbor; P/Q for ILP
        int k = 0;
        for (; k + 2 <= nh; k += 2) {
            float4 g0 = hxyz[pp][k], g1 = hxyz[pp][k + 1];
            v2f u0 = DTW, u1 = DTW;
            u0 += (v2f){g0.z, g0.z} * WF;            u1 += (v2f){g1.z, g1.z} * WF;
            u0 += (v2f){g0.x - ax, g0.x - ax} * WX;  u1 += (v2f){g1.x - ax, g1.x - ax} * WX;
            u0 += (v2f){g0.y - ay, g0.y - ay} * WY;  u1 += (v2f){g1.y - ay, g1.y - ay} * WY;
            u0 += (v2f){g0.z - az, g0.z - az} * WZ;  u1 += (v2f){g1.z - az, g1.z - az} * WZ;
            P = __builtin_elementwise_max(P, u0);
            Q = __builtin_elementwise_max(Q, u1);
        }
        if (k < nh) {
            float4 g0 = hxyz[pp][k];
            v2f u0 = DTW;
            u0 += (v2f){g0.z, g0.z} * WF;
            u0 += (v2f){g0.x - ax, g0.x - ax} * WX;
            u0 += (v2f){g0.y - ay, g0.y - ay} * WY;
            u0 += (v2f){g0.z - az, g0.z - az} * WZ;
            P = __builtin_elementwise_max(P, u0);
        }
        // no trailing barrier: ping-pong buffers handle WAR across dt
    }
    P = __builtin_elementwise_max(P, Q);

    // epilogue: positional linear + bias + relu, float32 store
    float4 wp0 = ((const float4*)W_pos)[d0];
    float4 wp1 = ((const float4*)W_pos)[d1];
    float tv = (float)(f + 1);
    float pos0 = ax * wp0.x + ay * wp0.y + az * wp0.z + tv * wp0.w + b_pos[d0];
    float pos1 = ax * wp1.x + ay * wp1.y + az * wp1.z + tv * wp1.w + b_pos[d1];
    float o0 = fmaxf(pos0 + P.x, 0.0f);
    float o1 = fmaxf(pos1 + P.y, 0.0f);
    size_t row = ((size_t)b * (TO * MM) + f * MM + m) * DIMD;
    outp[row + d0] = o0;
    outp[row + d1] = o1;
}

extern "C" void kernel_launch(void* const* d_in, const int* in_sizes, int n_in,
                              void* d_out, int out_size, void* d_ws, size_t ws_size,
                              hipStream_t stream) {
    const float* input = (const float*)d_in[0];
    const float* W_d   = (const float*)d_in[1];
    const float* W_f   = (const float*)d_in[2];
    const float* W_pos = (const float*)d_in[3];
    const float* b_pos = (const float*)d_in[4];
    float* anchor = (float*)d_ws;   // 16*64*3 floats = 12 KB

    fps_kernel<<<16, 256, 0, stream>>>(input, anchor);
    encode_kernel<<<1024, 256, 0, stream>>>(input, W_d, W_f, W_pos, b_pos, anchor,
                                            (float*)d_out);
}